// Round 4
// baseline (1395.983 us; speedup 1.0000x reference)
//
#include <hip/hip_runtime.h>

#define FDIM 128
constexpr int EP_NONE = 0, EP_RELU = 1, EP_FILM = 2, EP_LNRELU = 3;

struct Srcs { const float* p[5]; };

// ---------------- CSR build ----------------

__global__ __launch_bounds__(256)
void k_hist(const int* __restrict__ dst, int* __restrict__ cnt, int E) {
  int e = blockIdx.x * 256 + threadIdx.x;
  if (e < E) atomicAdd(&cnt[dst[e]], 1);
}

__global__ __launch_bounds__(1024)
void k_scan_block(const int* __restrict__ cnt, int* __restrict__ scanned,
                  int* __restrict__ partials, int n) {
  __shared__ int sd[1024];
  int tid = threadIdx.x;
  int i = blockIdx.x * 1024 + tid;
  int v = (i < n) ? cnt[i] : 0;
  sd[tid] = v; __syncthreads();
  for (int off = 1; off < 1024; off <<= 1) {
    int t = (tid >= off) ? sd[tid - off] : 0;
    __syncthreads();
    sd[tid] += t;
    __syncthreads();
  }
  if (i < n) scanned[i] = sd[tid] - v;  // exclusive within block
  if (tid == 1023) partials[blockIdx.x] = sd[1023];
}

__global__ __launch_bounds__(128)
void k_scan_small(const int* __restrict__ partials, int* __restrict__ p2, int nb) {
  __shared__ int sd[128];
  int tid = threadIdx.x;
  int v = (tid < nb) ? partials[tid] : 0;
  sd[tid] = v; __syncthreads();
  for (int off = 1; off < 128; off <<= 1) {
    int t = (tid >= off) ? sd[tid - off] : 0;
    __syncthreads();
    sd[tid] += t;
    __syncthreads();
  }
  p2[tid] = sd[tid] - v;  // exclusive; p2 has 128 slots
}

__global__ __launch_bounds__(256)
void k_finalize(const int* __restrict__ scanned, const int* __restrict__ p2,
                int* __restrict__ indptr, int* __restrict__ cursor, int n, int E) {
  int i = blockIdx.x * 256 + threadIdx.x;
  if (i < n) {
    int v = scanned[i] + p2[i >> 10];
    indptr[i] = v;
    cursor[i] = v;
  }
  if (i == 0) indptr[n] = E;
}

__global__ __launch_bounds__(256)
void k_scatter(const int* __restrict__ src, const int* __restrict__ dst,
               int* __restrict__ cursor, int* __restrict__ eids, int E) {
  int e = blockIdx.x * 256 + threadIdx.x;
  if (e < E) {
    int p = atomicAdd(&cursor[dst[e]], 1);
    eids[p] = src[e];
  }
}

// ---------------- aggregation: z = h + segment_sum(h[src], dst) ----------------
// one wave (64 lanes) per node; lane covers 2 feature columns (float2)

__global__ __launch_bounds__(256)
void k_aggr(const float* __restrict__ h, const int* __restrict__ indptr,
            const int* __restrict__ eids, float* __restrict__ z, int n) {
  int lane = threadIdx.x & 63;
  int node = blockIdx.x * 4 + (threadIdx.x >> 6);
  if (node >= n) return;
  float2 acc = *(const float2*)&h[(size_t)node * FDIM + lane * 2];
  int s = indptr[node], e = indptr[node + 1];
  for (int base = s; base < e; base += 64) {
    int cnt = min(64, e - base);
    int eid = (base + lane < e) ? eids[base + lane] : 0;
    for (int j = 0; j < cnt; ++j) {
      int sn = __shfl(eid, j, 64);
      float2 hv = *(const float2*)&h[(size_t)sn * FDIM + lane * 2];
      acc.x += hv.x; acc.y += hv.y;
    }
  }
  *(float2*)&z[(size_t)node * FDIM + lane * 2] = acc;
}

// ---------------- GEMM: out = epilogue(sum_j A_j @ W[j*128:...,:] + bias) ----------------
// BM=64 rows, full 128 cols, BK=64, 256 threads, thread tile 8 rows x 4 cols.
// NOTE: a block only reads A-rows [row0,row0+64) and only writes those same
// rows, and all A reads precede the epilogue writes -> in-place (A==out) safe.

template<int NSRC, int EPI>
__global__ __launch_bounds__(256)
void k_gemm(Srcs srcs, const float* __restrict__ W, const float* __restrict__ bias,
            float* __restrict__ out, int n,
            const int* __restrict__ bvec, const float* __restrict__ gam,
            const float* __restrict__ bet, int conv,
            const float* __restrict__ lng, const float* __restrict__ lnb) {
  __shared__ float As[64][68];       // transposed tile: As[k][r]
  __shared__ float Ws[64 * FDIM];    // Ws[k*128 + c]
  const int tid = threadIdx.x;
  const int tx = tid & 31;           // col group: cols tx*4 .. tx*4+3
  const int ty = tid >> 5;           // row group: rows ty*8 .. ty*8+7
  const int row0 = blockIdx.x * 64;
  const int sr = tid >> 2;           // staging local row 0..63
  const int sk = (tid & 3) * 16;     // staging k quarter

  float acc[8][4];
  #pragma unroll
  for (int i = 0; i < 8; ++i)
    #pragma unroll
    for (int j = 0; j < 4; ++j) acc[i][j] = 0.f;

  for (int js = 0; js < NSRC; ++js) {
    const float* __restrict__ A = srcs.p[js];
    #pragma unroll
    for (int cc = 0; cc < 2; ++cc) {
      const int kb = cc * 64;
      // stage A tile transposed
      {
        const int gr = row0 + sr;
        const float* Ar = A + (size_t)gr * FDIM + kb + sk;
        #pragma unroll
        for (int t = 0; t < 4; ++t) {
          float4 v = {0.f, 0.f, 0.f, 0.f};
          if (gr < n) v = *(const float4*)(Ar + t * 4);
          const int k = sk + t * 4;
          As[k + 0][sr] = v.x; As[k + 1][sr] = v.y;
          As[k + 2][sr] = v.z; As[k + 3][sr] = v.w;
        }
      }
      // stage W tile
      {
        const float* Wg = W + (size_t)(js * FDIM + kb) * FDIM;
        #pragma unroll
        for (int t = 0; t < 8; ++t) {
          const int idx = tid * 4 + t * 1024;
          *(float4*)&Ws[idx] = *(const float4*)&Wg[idx];
        }
      }
      __syncthreads();
      #pragma unroll 8
      for (int kk = 0; kk < 64; ++kk) {
        const float4 w = *(const float4*)&Ws[kk * FDIM + tx * 4];
        const float4 a0 = *(const float4*)&As[kk][ty * 8];
        const float4 a1 = *(const float4*)&As[kk][ty * 8 + 4];
        const float a[8] = {a0.x, a0.y, a0.z, a0.w, a1.x, a1.y, a1.z, a1.w};
        #pragma unroll
        for (int i = 0; i < 8; ++i) {
          acc[i][0] = fmaf(a[i], w.x, acc[i][0]);
          acc[i][1] = fmaf(a[i], w.y, acc[i][1]);
          acc[i][2] = fmaf(a[i], w.z, acc[i][2]);
          acc[i][3] = fmaf(a[i], w.w, acc[i][3]);
        }
      }
      __syncthreads();
    }
  }

  const float4 bv = *(const float4*)&bias[tx * 4];

  if constexpr (EPI == EP_LNRELU) {
    float v[8][4], s[8], sq[8];
    #pragma unroll
    for (int i = 0; i < 8; ++i) {
      v[i][0] = acc[i][0] + bv.x; v[i][1] = acc[i][1] + bv.y;
      v[i][2] = acc[i][2] + bv.z; v[i][3] = acc[i][3] + bv.w;
      s[i] = 0.f; sq[i] = 0.f;
      #pragma unroll
      for (int j = 0; j < 4; ++j) { s[i] += v[i][j]; sq[i] += v[i][j] * v[i][j]; }
    }
    // reduce across the 32 lanes of this row group (masks < 32 stay in-half)
    #pragma unroll
    for (int m = 1; m < 32; m <<= 1) {
      #pragma unroll
      for (int i = 0; i < 8; ++i) {
        s[i]  += __shfl_xor(s[i],  m, 64);
        sq[i] += __shfl_xor(sq[i], m, 64);
      }
    }
    const float4 g4 = *(const float4*)&lng[tx * 4];
    const float4 b4 = *(const float4*)&lnb[tx * 4];
    #pragma unroll
    for (int i = 0; i < 8; ++i) {
      const int r = row0 + ty * 8 + i;
      const float mu = s[i] * (1.f / FDIM);
      const float var = sq[i] * (1.f / FDIM) - mu * mu;
      const float rs = rsqrtf(var + 1e-5f);
      float4 o;
      o.x = fmaxf((v[i][0] - mu) * rs * g4.x + b4.x, 0.f);
      o.y = fmaxf((v[i][1] - mu) * rs * g4.y + b4.y, 0.f);
      o.z = fmaxf((v[i][2] - mu) * rs * g4.z + b4.z, 0.f);
      o.w = fmaxf((v[i][3] - mu) * rs * g4.w + b4.w, 0.f);
      if (r < n) *(float4*)&out[(size_t)r * FDIM + tx * 4] = o;
    }
  } else {
    #pragma unroll
    for (int i = 0; i < 8; ++i) {
      const int r = row0 + ty * 8 + i;
      if (r >= n) continue;
      float4 o;
      o.x = acc[i][0] + bv.x; o.y = acc[i][1] + bv.y;
      o.z = acc[i][2] + bv.z; o.w = acc[i][3] + bv.w;
      if constexpr (EPI == EP_RELU) {
        o.x = fmaxf(o.x, 0.f); o.y = fmaxf(o.y, 0.f);
        o.z = fmaxf(o.z, 0.f); o.w = fmaxf(o.w, 0.f);
      } else if constexpr (EPI == EP_FILM) {
        const int b = bvec[r];
        const float g = gam[b * 3 + conv];
        const float be = bet[b * 3 + conv];
        o.x = o.x * g + be; o.y = o.y * g + be;
        o.z = o.z * g + be; o.w = o.w * g + be;
      }
      *(float4*)&out[(size_t)r * FDIM + tx * 4] = o;
    }
  }
}

// ---------------- launch ----------------

extern "C" void kernel_launch(void* const* d_in, const int* in_sizes, int n_in,
                              void* d_out, int out_size, void* d_ws, size_t ws_size,
                              hipStream_t stream) {
  const float* x       = (const float*)d_in[0];
  const int*   eidx    = (const int*)d_in[1];
  const int*   bvec    = (const int*)d_in[2];
  const float* gam     = (const float*)d_in[3];
  const float* bet     = (const float*)d_in[4];
  const float* pre_W0  = (const float*)d_in[5];
  const float* pre_b0  = (const float*)d_in[6];
  const float* pre_W1  = (const float*)d_in[7];
  const float* pre_b1  = (const float*)d_in[8];
  const float* gin_W   = (const float*)d_in[9];
  const float* gin_b   = (const float*)d_in[10];
  const float* post_W0 = (const float*)d_in[11];
  const float* post_b0 = (const float*)d_in[12];
  const float* lng     = (const float*)d_in[13];
  const float* lnb     = (const float*)d_in[14];
  const float* post_W1 = (const float*)d_in[15];
  const float* post_b1 = (const float*)d_in[16];

  const int n = in_sizes[0] / FDIM;
  const int E = in_sizes[1] / 2;
  const int* esrc = eidx;
  const int* edst = eidx + E;
  float* out = (float*)d_out;

  // Workspace layout (minimized: 4*NF floats + ~2.0M ints ~= 213 MB).
  // zb and tmp BOTH alias d_out (see in-place safety note on k_gemm).
  const size_t NF = (size_t)n * FDIM;
  float* fws = (float*)d_ws;
  float* h0  = fws;
  float* h1  = fws + NF;
  float* h2  = fws + 2 * NF;
  float* h3  = fws + 3 * NF;
  float* zb  = out;
  float* tmp = out;
  int* iws      = (int*)(fws + 4 * NF);
  int* counts   = iws;               // n
  int* scanned  = iws + n;           // n
  int* indptr   = iws + 2 * n;       // n+1
  int* cursor   = iws + 3 * n + 1;   // n
  int* partials = iws + 4 * n + 1;   // 128
  int* p2       = partials + 128;    // 128
  int* eids     = p2 + 128;          // E

  // CSR build (by dst)
  hipMemsetAsync(counts, 0, (size_t)n * sizeof(int), stream);
  k_hist<<<(E + 255) / 256, 256, 0, stream>>>(edst, counts, E);
  const int nb = (n + 1023) / 1024;
  k_scan_block<<<nb, 1024, 0, stream>>>(counts, scanned, partials, n);
  k_scan_small<<<1, 128, 0, stream>>>(partials, p2, nb);
  k_finalize<<<(n + 255) / 256, 256, 0, stream>>>(scanned, p2, indptr, cursor, n, E);
  k_scatter<<<(E + 255) / 256, 256, 0, stream>>>(esrc, edst, cursor, eids, E);

  const int gb = (n + 63) / 64;

  // preprocess MLP: tmp = relu(x@W0+b0); h0 = tmp@W1+b1
  Srcs sx{{x, nullptr, nullptr, nullptr, nullptr}};
  k_gemm<1, EP_RELU><<<gb, 256, 0, stream>>>(sx, pre_W0, pre_b0, tmp, n,
                                             nullptr, nullptr, nullptr, 0, nullptr, nullptr);
  Srcs st0{{tmp, nullptr, nullptr, nullptr, nullptr}};
  k_gemm<1, EP_NONE><<<gb, 256, 0, stream>>>(st0, pre_W1, pre_b1, h0, n,
                                             nullptr, nullptr, nullptr, 0, nullptr, nullptr);

  // GIN convs with FiLM: zb(=out) <- aggr(hprev); tmp(=out) <- relu(zb@W+b) [in-place];
  // h_i <- film(tmp@W'+b')
  float* hprev = h0;
  float* houts[3] = {h1, h2, h3};
  for (int i = 0; i < 3; ++i) {
    k_aggr<<<(n + 3) / 4, 256, 0, stream>>>(hprev, indptr, eids, zb, n);
    Srcs sz{{zb, nullptr, nullptr, nullptr, nullptr}};
    k_gemm<1, EP_RELU><<<gb, 256, 0, stream>>>(
        sz, gin_W + (size_t)(i * 2) * FDIM * FDIM, gin_b + (size_t)(i * 2) * FDIM,
        tmp, n, nullptr, nullptr, nullptr, 0, nullptr, nullptr);
    Srcs st{{tmp, nullptr, nullptr, nullptr, nullptr}};
    k_gemm<1, EP_FILM><<<gb, 256, 0, stream>>>(
        st, gin_W + (size_t)(i * 2 + 1) * FDIM * FDIM, gin_b + (size_t)(i * 2 + 1) * FDIM,
        houts[i], n, bvec, gam, bet, i, nullptr, nullptr);
    hprev = houts[i];
  }

  // post: tmp(=out) <- LN+relu(concat@W0+b0) [fused]; out <- tmp@W1+b1 [in-place]
  Srcs sj{{x, h0, h1, h2, h3}};
  k_gemm<5, EP_LNRELU><<<gb, 256, 0, stream>>>(sj, post_W0, post_b0, tmp, n,
                                               nullptr, nullptr, nullptr, 0, lng, lnb);
  Srcs sf{{tmp, nullptr, nullptr, nullptr, nullptr}};
  k_gemm<1, EP_NONE><<<gb, 256, 0, stream>>>(sf, post_W1, post_b1, out, n,
                                             nullptr, nullptr, nullptr, 0, nullptr, nullptr);
}